// Round 1
// 1385.142 us; speedup vs baseline: 2.4853x; 2.4853x over previous
//
#include <hip/hip_runtime.h>

// GAT pipeline, MI355X (gfx950) — round 4: kill the scatter-atomic wall.
// edge_acc was 74% of runtime, bound by device-scope atomic rate (~20G/s):
// 51.2M float atomics/launch = 1.65GB of 32B fabric transactions. Replaced by
// dst-CSR build (ONE int-atomic pass, 6.4M atomics) + per-wave segmented
// reduction with no atomics, fused with finalize.

#define NNODES 100000
#define NEDGES 6400000
#define DIN    768
#define DH1    512
#define DH2    256
#define NEG_SLOPE 0.2f
#define SCAN_NB 391   // ceil(NNODES/256)

typedef __bf16 bf16x8 __attribute__((ext_vector_type(8)));
typedef float  f32x4  __attribute__((ext_vector_type(4)));

__device__ __forceinline__ float bf2f(unsigned short h) {
    return __uint_as_float(((unsigned)h) << 16);
}
__device__ __forceinline__ unsigned short f2bf(float f) {
    unsigned u = __float_as_uint(f);
    unsigned r = u + 0x7FFFu + ((u >> 16) & 1u);   // round-nearest-even
    return (unsigned short)(r >> 16);
}
__device__ __forceinline__ float ldf(const void* p, int i, int isf32) {
    return isf32 ? ((const float*)p)[i] : bf2f(((const unsigned short*)p)[i]);
}
__device__ __forceinline__ uint4 packbf8(const float* p) {
    float4 u = *(const float4*)p;
    float4 v = *(const float4*)(p + 4);
    uint4 r;
    r.x = (unsigned)f2bf(u.x) | ((unsigned)f2bf(u.y) << 16);
    r.y = (unsigned)f2bf(u.z) | ((unsigned)f2bf(u.w) << 16);
    r.z = (unsigned)f2bf(v.x) | ((unsigned)f2bf(v.y) << 16);
    r.w = (unsigned)f2bf(v.z) | ((unsigned)f2bf(v.w) << 16);
    return r;
}

// flags: [0]=x_f32 [1]=We1_f32 [2]=We2_f32 [3]=Wlin_f32 [4]=Watt_f32
//        [5]=edge_i64 [15]=0 constant
__global__ void detect_dtypes(const unsigned short* x, const unsigned short* we1,
                              const unsigned short* we2, const unsigned short* wlin,
                              const unsigned short* watt, const int* ei, int* flags) {
    __shared__ int cnt;
    int b = blockIdx.x, t = threadIdx.x;
    if (t == 0) cnt = 0;
    __syncthreads();
    if (b < 5) {
        const unsigned short* p = (b == 0) ? x : (b == 1) ? we1 : (b == 2) ? we2
                                  : (b == 3) ? wlin : watt;
        int K = (b == 4) ? 96 : 512;
        int c = 0;
        for (int i = t; i < K; i += 256) {
            int e = (p[2 * i] >> 7) & 0xFF;
            if (e >= 0x66 && e <= 0x8C) c++;
        }
        atomicAdd(&cnt, c);
        __syncthreads();
        if (t == 0) flags[b] = (cnt * 10 < K * 6) ? 1 : 0;
    } else {
        int c = 0;
        for (int i = t; i < 2048; i += 256)
            if (ei[2 * i + 1] != 0) c++;
        atomicAdd(&cnt, c);
        __syncthreads();
        if (t == 0) { flags[5] = (cnt == 0) ? 1 : 0; flags[15] = 0; }
    }
}

__global__ void transpose_conv(const void* in, unsigned short* out, int K, int N,
                               const int* flags, int fidx) {
    int f32 = flags[fidx];
    int idx = blockIdx.x * 256 + threadIdx.x;
    if (idx >= K * N) return;
    int k = idx / N, n = idx - k * N;
    unsigned short v = f32 ? f2bf(((const float*)in)[idx])
                           : ((const unsigned short*)in)[idx];
    out[(size_t)n * K + k] = v;
}

template <bool RELU>
__global__ __launch_bounds__(256)
void gemm_bt(const void* __restrict__ A,
             const unsigned short* __restrict__ Bt,
             const unsigned short* __restrict__ bias,
             unsigned short* __restrict__ C,
             int M, int K, int N, const int* flags, int aidx) {
    __shared__ unsigned short sA[128 * 32];
    __shared__ unsigned short sB[128 * 32];
    const int af32 = flags[aidx];
    const int tid = threadIdx.x;
    const int m0 = blockIdx.x * 128;
    const int n0 = blockIdx.y * 128;

    const int srow = tid >> 2;
    const int scol = (tid & 3) * 8;
    int ar0 = m0 + srow;      if (ar0 >= M) ar0 = M - 1;
    int ar1 = m0 + 64 + srow; if (ar1 >= M) ar1 = M - 1;
    const unsigned short* Ah = (const unsigned short*)A;
    const float*          Af = (const float*)A;
    const unsigned short* gA0h = Ah + (size_t)ar0 * K + scol;
    const unsigned short* gA1h = Ah + (size_t)ar1 * K + scol;
    const float*          gA0f = Af + (size_t)ar0 * K + scol;
    const float*          gA1f = Af + (size_t)ar1 * K + scol;
    const unsigned short* gB0 = Bt + (size_t)(n0 + srow) * K + scol;
    const unsigned short* gB1 = Bt + (size_t)(n0 + 64 + srow) * K + scol;

    const int wave = tid >> 6, lane = tid & 63;
    const int wr = wave >> 1, wc = wave & 1;
    const int lr = lane & 15;
    const int lk = (lane >> 4) * 8;
    f32x4 acc[4][4] = {};

    for (int k0 = 0; k0 < K; k0 += 32) {
        uint4 a0, a1;
        if (af32) { a0 = packbf8(gA0f + k0); a1 = packbf8(gA1f + k0); }
        else      { a0 = *(const uint4*)(gA0h + k0); a1 = *(const uint4*)(gA1h + k0); }
        uint4 b0 = *(const uint4*)(gB0 + k0);
        uint4 b1 = *(const uint4*)(gB1 + k0);
        __syncthreads();
        *(uint4*)&sA[srow * 32 + scol]        = a0;
        *(uint4*)&sA[(64 + srow) * 32 + scol] = a1;
        *(uint4*)&sB[srow * 32 + scol]        = b0;
        *(uint4*)&sB[(64 + srow) * 32 + scol] = b1;
        __syncthreads();
        bf16x8 aF[4], bF[4];
#pragma unroll
        for (int i = 0; i < 4; i++) aF[i] = *(const bf16x8*)&sA[(wr * 64 + i * 16 + lr) * 32 + lk];
#pragma unroll
        for (int j = 0; j < 4; j++) bF[j] = *(const bf16x8*)&sB[(wc * 64 + j * 16 + lr) * 32 + lk];
#pragma unroll
        for (int i = 0; i < 4; i++)
#pragma unroll
            for (int j = 0; j < 4; j++)
                acc[i][j] = __builtin_amdgcn_mfma_f32_16x16x32_bf16(aF[i], bF[j], acc[i][j], 0, 0, 0);
    }

    float bv[4];
#pragma unroll
    for (int j = 0; j < 4; j++) bv[j] = bf2f(bias[n0 + wc * 64 + j * 16 + lr]);
#pragma unroll
    for (int i = 0; i < 4; i++) {
        int rbase = m0 + wr * 64 + i * 16 + (lane >> 4) * 4;
#pragma unroll
        for (int r = 0; r < 4; r++) {
            int row = rbase + r;
            if (row < M) {
                size_t base = (size_t)row * N + n0 + wc * 64 + lr;
#pragma unroll
                for (int j = 0; j < 4; j++) {
                    float v = acc[i][j][r] + bv[j];
                    if (RELU) v = fmaxf(v, 0.f);
                    C[base + j * 16] = f2bf(v);
                }
            }
        }
    }
}

__global__ __launch_bounds__(256)
void node_att(const unsigned short* __restrict__ h2,
              const void* __restrict__ Wlin,
              const unsigned short* __restrict__ blin,
              const void* __restrict__ Watt,
              const void* __restrict__ attS,
              const void* __restrict__ attD,
              float* __restrict__ hh, float* __restrict__ asrc,
              float* __restrict__ adst, const int* flags) {
    __shared__ float sW[256 * 32];
    __shared__ float sh2[8 * 256];
    __shared__ float sH[8 * 32];
    __shared__ float sHH[8 * 6];
    const int wlf = flags[3], waf = flags[4];
    const int tid = threadIdx.x;
    for (int i = tid; i < 256 * 32; i += 256) sW[i] = ldf(Wlin, i, wlf);
    const int n0 = blockIdx.x * 8;
    {
        int e = tid * 8;
        int r = e >> 8;
        int c = e & 255;
        uint4 v = *(const uint4*)(h2 + (size_t)(n0 + r) * 256 + c);
        float* o = &sh2[r * 256 + c];
        o[0] = __uint_as_float(v.x << 16); o[1] = __uint_as_float(v.x & 0xFFFF0000u);
        o[2] = __uint_as_float(v.y << 16); o[3] = __uint_as_float(v.y & 0xFFFF0000u);
        o[4] = __uint_as_float(v.z << 16); o[5] = __uint_as_float(v.z & 0xFFFF0000u);
        o[6] = __uint_as_float(v.w << 16); o[7] = __uint_as_float(v.w & 0xFFFF0000u);
    }
    __syncthreads();
    const int nl = tid >> 5;
    const int c  = tid & 31;
    float acc = bf2f(blin[c]);
    const float* hrow = &sh2[nl * 256];
#pragma unroll 8
    for (int k = 0; k < 256; k++) acc += hrow[k] * sW[k * 32 + c];
    sH[nl * 32 + c] = acc;
    __syncthreads();
    if (tid < 48) {
        int n = tid / 6, j = tid - (tid / 6) * 6;
        float s = 0.f;
#pragma unroll
        for (int k = 0; k < 32; k++) s += sH[n * 32 + k] * ldf(Watt, k * 6 + j, waf);
        sHH[n * 6 + j] = s;
        hh[(size_t)(n0 + n) * 6 + j] = s;
    }
    __syncthreads();
    if (tid < 16) {
        int n = tid >> 1, hd = tid & 1;
        float s = 0.f, d = 0.f;
#pragma unroll
        for (int cc = 0; cc < 3; cc++) {
            float v = sHH[n * 6 + hd * 3 + cc];
            s += v * ldf(attS, hd * 3 + cc, waf);
            d += v * ldf(attD, hd * 3 + cc, waf);
        }
        asrc[(size_t)(n0 + n) * 2 + hd] = s;
        adst[(size_t)(n0 + n) * 2 + hd] = d;
    }
}

__global__ void init_zero(int* __restrict__ p, int n) {
    int i = blockIdx.x * 256 + threadIdx.x;
    if (i < n) p[i] = 0;
}

// Pass 1: per-edge rank within its destination bucket + per-dst counts.
// The ONLY atomic pass in the edge phase (6.4M int atomics vs 51.2M before).
__global__ __launch_bounds__(256)
void edge_rank(const int* __restrict__ ei, int* __restrict__ count,
               int* __restrict__ rank, const int* __restrict__ flags) {
    int e = blockIdx.x * 256 + threadIdx.x;
    if (e >= NEDGES) return;
    int d;
    if (flags[5]) d = (int)((const long long*)ei)[NEDGES + e];
    else          d = ei[NEDGES + e];
    rank[e] = atomicAdd(&count[d], 1);
}

// Exclusive scan of count[NNODES] -> offs[NNODES], 3 small kernels.
__global__ void scan_block_sums(const int* __restrict__ count, int* __restrict__ bsum) {
    __shared__ int s[256];
    int i = blockIdx.x * 256 + threadIdx.x;
    int t = threadIdx.x;
    s[t] = (i < NNODES) ? count[i] : 0;
    __syncthreads();
    for (int off = 128; off > 0; off >>= 1) {
        if (t < off) s[t] += s[t + off];
        __syncthreads();
    }
    if (t == 0) bsum[blockIdx.x] = s[0];
}

__global__ void scan_bsum(const int* __restrict__ bsum, int* __restrict__ bscan, int nb) {
    __shared__ int s[512];
    int t = threadIdx.x;
    int v = (t < nb) ? bsum[t] : 0;
    s[t] = v;
    __syncthreads();
    for (int off = 1; off < 512; off <<= 1) {
        int x = (t >= off) ? s[t - off] : 0;
        __syncthreads();
        s[t] += x;
        __syncthreads();
    }
    if (t < nb) bscan[t] = s[t] - v;   // exclusive
}

__global__ void scan_final(const int* __restrict__ count, const int* __restrict__ bscan,
                           int* __restrict__ offs) {
    __shared__ int s[256];
    int i = blockIdx.x * 256 + threadIdx.x;
    int t = threadIdx.x;
    int v = (i < NNODES) ? count[i] : 0;
    s[t] = v;
    __syncthreads();
    for (int off = 1; off < 256; off <<= 1) {
        int x = (t >= off) ? s[t - off] : 0;
        __syncthreads();
        s[t] += x;
        __syncthreads();
    }
    if (i < NNODES) offs[i] = s[t] - v + bscan[blockIdx.x];
}

// Pass 2: stable scatter of src ids into dst-CSR order. No atomics.
__global__ __launch_bounds__(256)
void edge_scatter(const int* __restrict__ ei, const int* __restrict__ rank,
                  const int* __restrict__ offs, int* __restrict__ sorted,
                  const int* __restrict__ flags) {
    int e = blockIdx.x * 256 + threadIdx.x;
    if (e >= NEDGES) return;
    int s, d;
    if (flags[5]) {
        const long long* e64 = (const long long*)ei;
        s = (int)e64[e];
        d = (int)e64[NEDGES + e];
    } else {
        s = ei[e];
        d = ei[NEDGES + e];
    }
    sorted[offs[d] + rank[e]] = s;
}

// One wave per destination node: register accumulation + butterfly reduce,
// self-loop added analytically, softmax-normalize, head-mean, bias, store.
// Fuses the old finalize kernel; zero atomics.
__global__ __launch_bounds__(256)
void gather_finalize(const int* __restrict__ sorted, const int* __restrict__ offs,
                     const int* __restrict__ count,
                     const float* __restrict__ asrc, const float* __restrict__ adst,
                     const float* __restrict__ hh,
                     const unsigned short* __restrict__ bias,
                     void* __restrict__ out, const int* __restrict__ flags) {
    int w = blockIdx.x * 4 + (threadIdx.x >> 6);
    if (w >= NNODES) return;
    int lane = threadIdx.x & 63;
    int base = offs[w];
    int cnt  = count[w];
    float2 ad = *(const float2*)(adst + 2 * (size_t)w);

    float d0 = 0.f, d1 = 0.f;
    float n0 = 0.f, n1 = 0.f, n2 = 0.f, n3 = 0.f, n4 = 0.f, n5 = 0.f;
    for (int k = lane; k < cnt; k += 64) {
        int s = sorted[base + k];
        float2 as = *(const float2*)(asrc + 2 * (size_t)s);
        float a0 = as.x + ad.x; a0 = a0 > 0.f ? a0 : NEG_SLOPE * a0;
        float a1 = as.y + ad.y; a1 = a1 > 0.f ? a1 : NEG_SLOPE * a1;
        float p0 = __expf(fminf(a0, 60.f));
        float p1 = __expf(fminf(a1, 60.f));
        const float* hs = hh + 6 * (size_t)s;
        d0 += p0; d1 += p1;
        n0 += p0 * hs[0]; n1 += p0 * hs[1]; n2 += p0 * hs[2];
        n3 += p1 * hs[3]; n4 += p1 * hs[4]; n5 += p1 * hs[5];
    }
#pragma unroll
    for (int m = 32; m > 0; m >>= 1) {
        d0 += __shfl_xor(d0, m, 64); d1 += __shfl_xor(d1, m, 64);
        n0 += __shfl_xor(n0, m, 64); n1 += __shfl_xor(n1, m, 64);
        n2 += __shfl_xor(n2, m, 64); n3 += __shfl_xor(n3, m, 64);
        n4 += __shfl_xor(n4, m, 64); n5 += __shfl_xor(n5, m, 64);
    }
    if (lane == 0) {
        // self-loop (s == w)
        float2 as = *(const float2*)(asrc + 2 * (size_t)w);
        float a0 = as.x + ad.x; a0 = a0 > 0.f ? a0 : NEG_SLOPE * a0;
        float a1 = as.y + ad.y; a1 = a1 > 0.f ? a1 : NEG_SLOPE * a1;
        float p0 = __expf(fminf(a0, 60.f));
        float p1 = __expf(fminf(a1, 60.f));
        const float* hw = hh + 6 * (size_t)w;
        d0 += p0; d1 += p1;
        n0 += p0 * hw[0]; n1 += p0 * hw[1]; n2 += p0 * hw[2];
        n3 += p1 * hw[3]; n4 += p1 * hw[4]; n5 += p1 * hw[5];

        float o0 = 0.5f * (n0 / d0 + n3 / d1) + bf2f(bias[0]);
        float o1 = 0.5f * (n1 / d0 + n4 / d1) + bf2f(bias[1]);
        float o2 = 0.5f * (n2 / d0 + n5 / d1) + bf2f(bias[2]);
        if (flags[0]) {
            float* o = (float*)out;
            o[3 * (size_t)w + 0] = o0; o[3 * (size_t)w + 1] = o1; o[3 * (size_t)w + 2] = o2;
        } else {
            unsigned short* o = (unsigned short*)out;
            o[3 * (size_t)w + 0] = f2bf(o0); o[3 * (size_t)w + 1] = f2bf(o1); o[3 * (size_t)w + 2] = f2bf(o2);
        }
    }
}

extern "C" void kernel_launch(void* const* d_in, const int* in_sizes, int n_in,
                              void* d_out, int out_size, void* d_ws, size_t ws_size,
                              hipStream_t stream) {
    const unsigned short* x    = (const unsigned short*)d_in[0];
    const int*            ei   = (const int*)d_in[1];
    const unsigned short* We1  = (const unsigned short*)d_in[2];
    const unsigned short* be1  = (const unsigned short*)d_in[3];
    const unsigned short* We2  = (const unsigned short*)d_in[4];
    const unsigned short* be2  = (const unsigned short*)d_in[5];
    const unsigned short* Wlin = (const unsigned short*)d_in[6];
    const unsigned short* blin = (const unsigned short*)d_in[7];
    const unsigned short* Watt = (const unsigned short*)d_in[8];
    const unsigned short* attS = (const unsigned short*)d_in[9];
    const unsigned short* attD = (const unsigned short*)d_in[10];
    const unsigned short* bias = (const unsigned short*)d_in[11];

    char* ws = (char*)d_ws;
    unsigned short* W1t   = (unsigned short*)(ws + 0);          //     786,432
    unsigned short* W2t   = (unsigned short*)(ws + 786432);     //     262,144
    unsigned short* h2    = (unsigned short*)(ws + 1048576);    //  51,200,000
    float*    hh    = (float*)(ws + 52248576);                  //   2,400,000
    float*    asrc  = (float*)(ws + 54648576);                  //     800,000
    float*    adst  = (float*)(ws + 55448576);                  //     800,000
    int*      count = (int*)(ws + 56248576);                    //     400,000
    int*      offs  = (int*)(ws + 56648576);                    //     400,000
    int*      bsum  = (int*)(ws + 57048576);                    //       4,096
    int*      bscan = (int*)(ws + 57052672);                    //       4,096
    int*      flags = (int*)(ws + 59448576);                    //          64
    unsigned short* h1 = (unsigned short*)(ws + 59448640);      // 102,400,000 (end ~161.8MB)
    // rank/sorted alias h1 (dead after gemm2; stream-serialized).
    int* rank   = (int*)(ws + 59448640);                        //  25,600,000
    int* sorted = (int*)(ws + 59448640 + 25600000);             //  25,600,000
    (void)ws_size; (void)in_sizes; (void)n_in; (void)out_size;

    detect_dtypes<<<6, 256, 0, stream>>>(x, We1, We2, Wlin, Watt, ei, flags);

    transpose_conv<<<(DIN * DH1 + 255) / 256, 256, 0, stream>>>(We1, W1t, DIN, DH1, flags, 1);
    transpose_conv<<<(DH1 * DH2 + 255) / 256, 256, 0, stream>>>(We2, W2t, DH1, DH2, flags, 2);

    dim3 blk(256);
    dim3 g1((NNODES + 127) / 128, DH1 / 128);
    gemm_bt<true><<<g1, blk, 0, stream>>>(x, W1t, be1, h1, NNODES, DIN, DH1, flags, 0);
    dim3 g2((NNODES + 127) / 128, DH2 / 128);
    gemm_bt<false><<<g2, blk, 0, stream>>>(h1, W2t, be2, h2, NNODES, DH1, DH2, flags, 15);

    node_att<<<NNODES / 8, 256, 0, stream>>>(h2, Wlin, blin, Watt, attS, attD,
                                             hh, asrc, adst, flags);

    // ---- edge phase: CSR build + segmented reduce ----
    init_zero<<<(NNODES + 255) / 256, 256, 0, stream>>>(count, NNODES);
    edge_rank<<<NEDGES / 256, 256, 0, stream>>>(ei, count, rank, flags);
    scan_block_sums<<<SCAN_NB, 256, 0, stream>>>(count, bsum);
    scan_bsum<<<1, 512, 0, stream>>>(bsum, bscan, SCAN_NB);
    scan_final<<<SCAN_NB, 256, 0, stream>>>(count, bscan, offs);
    edge_scatter<<<NEDGES / 256, 256, 0, stream>>>(ei, rank, offs, sorted, flags);
    gather_finalize<<<(NNODES + 3) / 4, 256, 0, stream>>>(sorted, offs, count,
                                                          asrc, adst, hh, bias,
                                                          d_out, flags);
}

// Round 2
// 1281.115 us; speedup vs baseline: 2.6871x; 1.0812x over previous
//
#include <hip/hip_runtime.h>

// GAT pipeline, MI355X (gfx950) — round 5: gemm locality.
// Round-4 counters: gemm1 337us, FETCH 606MB vs 307MB ideal (A-panel refetched
// across N-tiles dispatched 782 blocks apart on different XCDs), and 9.6M LDS
// bank-conflict cycles ([128][32] ushort tile -> 64B row stride -> quarter-wave
// ds_read_b128 hits banks {0,16} only). Fixes: bijective XCD-chunk swizzle with
// N-fastest logical order (A-panel served from one XCD's L2), LDS pitch 32->40.

#define NNODES 100000
#define NEDGES 6400000
#define DIN    768
#define DH1    512
#define DH2    256
#define NEG_SLOPE 0.2f
#define SCAN_NB 391   // ceil(NNODES/256)
#define LDSP   40     // padded LDS pitch (ushorts): 80B rows spread bank starts

typedef __bf16 bf16x8 __attribute__((ext_vector_type(8)));
typedef float  f32x4  __attribute__((ext_vector_type(4)));

__device__ __forceinline__ float bf2f(unsigned short h) {
    return __uint_as_float(((unsigned)h) << 16);
}
__device__ __forceinline__ unsigned short f2bf(float f) {
    unsigned u = __float_as_uint(f);
    unsigned r = u + 0x7FFFu + ((u >> 16) & 1u);   // round-nearest-even
    return (unsigned short)(r >> 16);
}
__device__ __forceinline__ float ldf(const void* p, int i, int isf32) {
    return isf32 ? ((const float*)p)[i] : bf2f(((const unsigned short*)p)[i]);
}
__device__ __forceinline__ uint4 packbf8(const float* p) {
    float4 u = *(const float4*)p;
    float4 v = *(const float4*)(p + 4);
    uint4 r;
    r.x = (unsigned)f2bf(u.x) | ((unsigned)f2bf(u.y) << 16);
    r.y = (unsigned)f2bf(u.z) | ((unsigned)f2bf(u.w) << 16);
    r.z = (unsigned)f2bf(v.x) | ((unsigned)f2bf(v.y) << 16);
    r.w = (unsigned)f2bf(v.z) | ((unsigned)f2bf(v.w) << 16);
    return r;
}

// flags: [0]=x_f32 [1]=We1_f32 [2]=We2_f32 [3]=Wlin_f32 [4]=Watt_f32
//        [5]=edge_i64 [15]=0 constant
__global__ void detect_dtypes(const unsigned short* x, const unsigned short* we1,
                              const unsigned short* we2, const unsigned short* wlin,
                              const unsigned short* watt, const int* ei, int* flags) {
    __shared__ int cnt;
    int b = blockIdx.x, t = threadIdx.x;
    if (t == 0) cnt = 0;
    __syncthreads();
    if (b < 5) {
        const unsigned short* p = (b == 0) ? x : (b == 1) ? we1 : (b == 2) ? we2
                                  : (b == 3) ? wlin : watt;
        int K = (b == 4) ? 96 : 512;
        int c = 0;
        for (int i = t; i < K; i += 256) {
            int e = (p[2 * i] >> 7) & 0xFF;
            if (e >= 0x66 && e <= 0x8C) c++;
        }
        atomicAdd(&cnt, c);
        __syncthreads();
        if (t == 0) flags[b] = (cnt * 10 < K * 6) ? 1 : 0;
    } else {
        int c = 0;
        for (int i = t; i < 2048; i += 256)
            if (ei[2 * i + 1] != 0) c++;
        atomicAdd(&cnt, c);
        __syncthreads();
        if (t == 0) { flags[5] = (cnt == 0) ? 1 : 0; flags[15] = 0; }
    }
}

__global__ void transpose_conv(const void* in, unsigned short* out, int K, int N,
                               const int* flags, int fidx) {
    int f32 = flags[fidx];
    int idx = blockIdx.x * 256 + threadIdx.x;
    if (idx >= K * N) return;
    int k = idx / N, n = idx - k * N;
    unsigned short v = f32 ? f2bf(((const float*)in)[idx])
                           : ((const unsigned short*)in)[idx];
    out[(size_t)n * K + k] = v;
}

template <bool RELU>
__global__ __launch_bounds__(256)
void gemm_bt(const void* __restrict__ A,
             const unsigned short* __restrict__ Bt,
             const unsigned short* __restrict__ bias,
             unsigned short* __restrict__ C,
             int M, int K, int N, const int* flags, int aidx, int nt_n) {
    __shared__ unsigned short sA[128 * LDSP];
    __shared__ unsigned short sB[128 * LDSP];
    const int af32 = flags[aidx];
    const int tid = threadIdx.x;

    // Bijective XCD-chunk swizzle (m204): each XCD gets a contiguous logical
    // range; logical order is N-fastest so the nt_n blocks sharing one A-panel
    // co-run on one XCD and share it through that XCD's L2.
    const int nwg = gridDim.x;
    const int bid = blockIdx.x;
    const int xcd = bid & 7, bidx = bid >> 3;
    const int q = nwg >> 3, r = nwg & 7;
    const int logical = (xcd < r ? xcd * (q + 1) : r * (q + 1) + (xcd - r) * q) + bidx;
    const int m0 = (logical / nt_n) * 128;
    const int n0 = (logical % nt_n) * 128;

    const int srow = tid >> 2;
    const int scol = (tid & 3) * 8;
    int ar0 = m0 + srow;      if (ar0 >= M) ar0 = M - 1;
    int ar1 = m0 + 64 + srow; if (ar1 >= M) ar1 = M - 1;
    const unsigned short* Ah = (const unsigned short*)A;
    const float*          Af = (const float*)A;
    const unsigned short* gA0h = Ah + (size_t)ar0 * K + scol;
    const unsigned short* gA1h = Ah + (size_t)ar1 * K + scol;
    const float*          gA0f = Af + (size_t)ar0 * K + scol;
    const float*          gA1f = Af + (size_t)ar1 * K + scol;
    const unsigned short* gB0 = Bt + (size_t)(n0 + srow) * K + scol;
    const unsigned short* gB1 = Bt + (size_t)(n0 + 64 + srow) * K + scol;

    const int wave = tid >> 6, lane = tid & 63;
    const int wr = wave >> 1, wc = wave & 1;
    const int lr = lane & 15;
    const int lk = (lane >> 4) * 8;
    f32x4 acc[4][4] = {};

    for (int k0 = 0; k0 < K; k0 += 32) {
        uint4 a0, a1;
        if (af32) { a0 = packbf8(gA0f + k0); a1 = packbf8(gA1f + k0); }
        else      { a0 = *(const uint4*)(gA0h + k0); a1 = *(const uint4*)(gA1h + k0); }
        uint4 b0 = *(const uint4*)(gB0 + k0);
        uint4 b1 = *(const uint4*)(gB1 + k0);
        __syncthreads();
        *(uint4*)&sA[srow * LDSP + scol]        = a0;
        *(uint4*)&sA[(64 + srow) * LDSP + scol] = a1;
        *(uint4*)&sB[srow * LDSP + scol]        = b0;
        *(uint4*)&sB[(64 + srow) * LDSP + scol] = b1;
        __syncthreads();
        bf16x8 aF[4], bF[4];
#pragma unroll
        for (int i = 0; i < 4; i++) aF[i] = *(const bf16x8*)&sA[(wr * 64 + i * 16 + lr) * LDSP + lk];
#pragma unroll
        for (int j = 0; j < 4; j++) bF[j] = *(const bf16x8*)&sB[(wc * 64 + j * 16 + lr) * LDSP + lk];
#pragma unroll
        for (int i = 0; i < 4; i++)
#pragma unroll
            for (int j = 0; j < 4; j++)
                acc[i][j] = __builtin_amdgcn_mfma_f32_16x16x32_bf16(aF[i], bF[j], acc[i][j], 0, 0, 0);
    }

    float bv[4];
#pragma unroll
    for (int j = 0; j < 4; j++) bv[j] = bf2f(bias[n0 + wc * 64 + j * 16 + lr]);
#pragma unroll
    for (int i = 0; i < 4; i++) {
        int rbase = m0 + wr * 64 + i * 16 + (lane >> 4) * 4;
#pragma unroll
        for (int r = 0; r < 4; r++) {
            int row = rbase + r;
            if (row < M) {
                size_t base = (size_t)row * N + n0 + wc * 64 + lr;
#pragma unroll
                for (int j = 0; j < 4; j++) {
                    float v = acc[i][j][r] + bv[j];
                    if (RELU) v = fmaxf(v, 0.f);
                    C[base + j * 16] = f2bf(v);
                }
            }
        }
    }
}

__global__ __launch_bounds__(256)
void node_att(const unsigned short* __restrict__ h2,
              const void* __restrict__ Wlin,
              const unsigned short* __restrict__ blin,
              const void* __restrict__ Watt,
              const void* __restrict__ attS,
              const void* __restrict__ attD,
              float* __restrict__ hh, float* __restrict__ asrc,
              float* __restrict__ adst, const int* flags) {
    __shared__ float sW[256 * 32];
    __shared__ float sh2[8 * 256];
    __shared__ float sH[8 * 32];
    __shared__ float sHH[8 * 6];
    const int wlf = flags[3], waf = flags[4];
    const int tid = threadIdx.x;
    for (int i = tid; i < 256 * 32; i += 256) sW[i] = ldf(Wlin, i, wlf);
    const int n0 = blockIdx.x * 8;
    {
        int e = tid * 8;
        int r = e >> 8;
        int c = e & 255;
        uint4 v = *(const uint4*)(h2 + (size_t)(n0 + r) * 256 + c);
        float* o = &sh2[r * 256 + c];
        o[0] = __uint_as_float(v.x << 16); o[1] = __uint_as_float(v.x & 0xFFFF0000u);
        o[2] = __uint_as_float(v.y << 16); o[3] = __uint_as_float(v.y & 0xFFFF0000u);
        o[4] = __uint_as_float(v.z << 16); o[5] = __uint_as_float(v.z & 0xFFFF0000u);
        o[6] = __uint_as_float(v.w << 16); o[7] = __uint_as_float(v.w & 0xFFFF0000u);
    }
    __syncthreads();
    const int nl = tid >> 5;
    const int c  = tid & 31;
    float acc = bf2f(blin[c]);
    const float* hrow = &sh2[nl * 256];
#pragma unroll 8
    for (int k = 0; k < 256; k++) acc += hrow[k] * sW[k * 32 + c];
    sH[nl * 32 + c] = acc;
    __syncthreads();
    if (tid < 48) {
        int n = tid / 6, j = tid - (tid / 6) * 6;
        float s = 0.f;
#pragma unroll
        for (int k = 0; k < 32; k++) s += sH[n * 32 + k] * ldf(Watt, k * 6 + j, waf);
        sHH[n * 6 + j] = s;
        hh[(size_t)(n0 + n) * 6 + j] = s;
    }
    __syncthreads();
    if (tid < 16) {
        int n = tid >> 1, hd = tid & 1;
        float s = 0.f, d = 0.f;
#pragma unroll
        for (int cc = 0; cc < 3; cc++) {
            float v = sHH[n * 6 + hd * 3 + cc];
            s += v * ldf(attS, hd * 3 + cc, waf);
            d += v * ldf(attD, hd * 3 + cc, waf);
        }
        asrc[(size_t)(n0 + n) * 2 + hd] = s;
        adst[(size_t)(n0 + n) * 2 + hd] = d;
    }
}

__global__ void init_zero(int* __restrict__ p, int n) {
    int i = blockIdx.x * 256 + threadIdx.x;
    if (i < n) p[i] = 0;
}

// Pass 1: per-edge rank within its destination bucket + per-dst counts.
// The ONLY atomic pass in the edge phase (6.4M int atomics vs 51.2M before).
__global__ __launch_bounds__(256)
void edge_rank(const int* __restrict__ ei, int* __restrict__ count,
               int* __restrict__ rank, const int* __restrict__ flags) {
    int e = blockIdx.x * 256 + threadIdx.x;
    if (e >= NEDGES) return;
    int d;
    if (flags[5]) d = (int)((const long long*)ei)[NEDGES + e];
    else          d = ei[NEDGES + e];
    rank[e] = atomicAdd(&count[d], 1);
}

// Exclusive scan of count[NNODES] -> offs[NNODES], 3 small kernels.
__global__ void scan_block_sums(const int* __restrict__ count, int* __restrict__ bsum) {
    __shared__ int s[256];
    int i = blockIdx.x * 256 + threadIdx.x;
    int t = threadIdx.x;
    s[t] = (i < NNODES) ? count[i] : 0;
    __syncthreads();
    for (int off = 128; off > 0; off >>= 1) {
        if (t < off) s[t] += s[t + off];
        __syncthreads();
    }
    if (t == 0) bsum[blockIdx.x] = s[0];
}

__global__ void scan_bsum(const int* __restrict__ bsum, int* __restrict__ bscan, int nb) {
    __shared__ int s[512];
    int t = threadIdx.x;
    int v = (t < nb) ? bsum[t] : 0;
    s[t] = v;
    __syncthreads();
    for (int off = 1; off < 512; off <<= 1) {
        int x = (t >= off) ? s[t - off] : 0;
        __syncthreads();
        s[t] += x;
        __syncthreads();
    }
    if (t < nb) bscan[t] = s[t] - v;   // exclusive
}

__global__ void scan_final(const int* __restrict__ count, const int* __restrict__ bscan,
                           int* __restrict__ offs) {
    __shared__ int s[256];
    int i = blockIdx.x * 256 + threadIdx.x;
    int t = threadIdx.x;
    int v = (i < NNODES) ? count[i] : 0;
    s[t] = v;
    __syncthreads();
    for (int off = 1; off < 256; off <<= 1) {
        int x = (t >= off) ? s[t - off] : 0;
        __syncthreads();
        s[t] += x;
        __syncthreads();
    }
    if (i < NNODES) offs[i] = s[t] - v + bscan[blockIdx.x];
}

// Pass 2: stable scatter of src ids into dst-CSR order. No atomics.
__global__ __launch_bounds__(256)
void edge_scatter(const int* __restrict__ ei, const int* __restrict__ rank,
                  const int* __restrict__ offs, int* __restrict__ sorted,
                  const int* __restrict__ flags) {
    int e = blockIdx.x * 256 + threadIdx.x;
    if (e >= NEDGES) return;
    int s, d;
    if (flags[5]) {
        const long long* e64 = (const long long*)ei;
        s = (int)e64[e];
        d = (int)e64[NEDGES + e];
    } else {
        s = ei[e];
        d = ei[NEDGES + e];
    }
    sorted[offs[d] + rank[e]] = s;
}

// One wave per destination node: register accumulation + butterfly reduce,
// self-loop added analytically, softmax-normalize, head-mean, bias, store.
__global__ __launch_bounds__(256)
void gather_finalize(const int* __restrict__ sorted, const int* __restrict__ offs,
                     const int* __restrict__ count,
                     const float* __restrict__ asrc, const float* __restrict__ adst,
                     const float* __restrict__ hh,
                     const unsigned short* __restrict__ bias,
                     void* __restrict__ out, const int* __restrict__ flags) {
    int w = blockIdx.x * 4 + (threadIdx.x >> 6);
    if (w >= NNODES) return;
    int lane = threadIdx.x & 63;
    int base = offs[w];
    int cnt  = count[w];
    float2 ad = *(const float2*)(adst + 2 * (size_t)w);

    float d0 = 0.f, d1 = 0.f;
    float n0 = 0.f, n1 = 0.f, n2 = 0.f, n3 = 0.f, n4 = 0.f, n5 = 0.f;
    for (int k = lane; k < cnt; k += 64) {
        int s = sorted[base + k];
        float2 as = *(const float2*)(asrc + 2 * (size_t)s);
        float a0 = as.x + ad.x; a0 = a0 > 0.f ? a0 : NEG_SLOPE * a0;
        float a1 = as.y + ad.y; a1 = a1 > 0.f ? a1 : NEG_SLOPE * a1;
        float p0 = __expf(fminf(a0, 60.f));
        float p1 = __expf(fminf(a1, 60.f));
        const float* hs = hh + 6 * (size_t)s;
        d0 += p0; d1 += p1;
        n0 += p0 * hs[0]; n1 += p0 * hs[1]; n2 += p0 * hs[2];
        n3 += p1 * hs[3]; n4 += p1 * hs[4]; n5 += p1 * hs[5];
    }
#pragma unroll
    for (int m = 32; m > 0; m >>= 1) {
        d0 += __shfl_xor(d0, m, 64); d1 += __shfl_xor(d1, m, 64);
        n0 += __shfl_xor(n0, m, 64); n1 += __shfl_xor(n1, m, 64);
        n2 += __shfl_xor(n2, m, 64); n3 += __shfl_xor(n3, m, 64);
        n4 += __shfl_xor(n4, m, 64); n5 += __shfl_xor(n5, m, 64);
    }
    if (lane == 0) {
        // self-loop (s == w)
        float2 as = *(const float2*)(asrc + 2 * (size_t)w);
        float a0 = as.x + ad.x; a0 = a0 > 0.f ? a0 : NEG_SLOPE * a0;
        float a1 = as.y + ad.y; a1 = a1 > 0.f ? a1 : NEG_SLOPE * a1;
        float p0 = __expf(fminf(a0, 60.f));
        float p1 = __expf(fminf(a1, 60.f));
        const float* hw = hh + 6 * (size_t)w;
        d0 += p0; d1 += p1;
        n0 += p0 * hw[0]; n1 += p0 * hw[1]; n2 += p0 * hw[2];
        n3 += p1 * hw[3]; n4 += p1 * hw[4]; n5 += p1 * hw[5];

        float o0 = 0.5f * (n0 / d0 + n3 / d1) + bf2f(bias[0]);
        float o1 = 0.5f * (n1 / d0 + n4 / d1) + bf2f(bias[1]);
        float o2 = 0.5f * (n2 / d0 + n5 / d1) + bf2f(bias[2]);
        if (flags[0]) {
            float* o = (float*)out;
            o[3 * (size_t)w + 0] = o0; o[3 * (size_t)w + 1] = o1; o[3 * (size_t)w + 2] = o2;
        } else {
            unsigned short* o = (unsigned short*)out;
            o[3 * (size_t)w + 0] = f2bf(o0); o[3 * (size_t)w + 1] = f2bf(o1); o[3 * (size_t)w + 2] = f2bf(o2);
        }
    }
}

extern "C" void kernel_launch(void* const* d_in, const int* in_sizes, int n_in,
                              void* d_out, int out_size, void* d_ws, size_t ws_size,
                              hipStream_t stream) {
    const unsigned short* x    = (const unsigned short*)d_in[0];
    const int*            ei   = (const int*)d_in[1];
    const unsigned short* We1  = (const unsigned short*)d_in[2];
    const unsigned short* be1  = (const unsigned short*)d_in[3];
    const unsigned short* We2  = (const unsigned short*)d_in[4];
    const unsigned short* be2  = (const unsigned short*)d_in[5];
    const unsigned short* Wlin = (const unsigned short*)d_in[6];
    const unsigned short* blin = (const unsigned short*)d_in[7];
    const unsigned short* Watt = (const unsigned short*)d_in[8];
    const unsigned short* attS = (const unsigned short*)d_in[9];
    const unsigned short* attD = (const unsigned short*)d_in[10];
    const unsigned short* bias = (const unsigned short*)d_in[11];

    char* ws = (char*)d_ws;
    unsigned short* W1t   = (unsigned short*)(ws + 0);          //     786,432
    unsigned short* W2t   = (unsigned short*)(ws + 786432);     //     262,144
    unsigned short* h2    = (unsigned short*)(ws + 1048576);    //  51,200,000
    float*    hh    = (float*)(ws + 52248576);                  //   2,400,000
    float*    asrc  = (float*)(ws + 54648576);                  //     800,000
    float*    adst  = (float*)(ws + 55448576);                  //     800,000
    int*      count = (int*)(ws + 56248576);                    //     400,000
    int*      offs  = (int*)(ws + 56648576);                    //     400,000
    int*      bsum  = (int*)(ws + 57048576);                    //       4,096
    int*      bscan = (int*)(ws + 57052672);                    //       4,096
    int*      flags = (int*)(ws + 59448576);                    //          64
    unsigned short* h1 = (unsigned short*)(ws + 59448640);      // 102,400,000 (end ~161.8MB)
    // rank/sorted alias h1 (dead after gemm2; stream-serialized).
    int* rank   = (int*)(ws + 59448640);                        //  25,600,000
    int* sorted = (int*)(ws + 59448640 + 25600000);             //  25,600,000
    (void)ws_size; (void)in_sizes; (void)n_in; (void)out_size;

    detect_dtypes<<<6, 256, 0, stream>>>(x, We1, We2, Wlin, Watt, ei, flags);

    transpose_conv<<<(DIN * DH1 + 255) / 256, 256, 0, stream>>>(We1, W1t, DIN, DH1, flags, 1);
    transpose_conv<<<(DH1 * DH2 + 255) / 256, 256, 0, stream>>>(We2, W2t, DH1, DH2, flags, 2);

    dim3 blk(256);
    // 1-D grids; in-kernel XCD-chunk swizzle, logical order N-fastest.
    int nwg1 = ((NNODES + 127) / 128) * (DH1 / 128);   // 782*4 = 3128
    gemm_bt<true><<<nwg1, blk, 0, stream>>>(x, W1t, be1, h1, NNODES, DIN, DH1,
                                            flags, 0, DH1 / 128);
    int nwg2 = ((NNODES + 127) / 128) * (DH2 / 128);   // 782*2 = 1564
    gemm_bt<false><<<nwg2, blk, 0, stream>>>(h1, W2t, be2, h2, NNODES, DH1, DH2,
                                             flags, 15, DH2 / 128);

    node_att<<<NNODES / 8, 256, 0, stream>>>(h2, Wlin, blin, Watt, attS, attD,
                                             hh, asrc, adst, flags);

    // ---- edge phase: CSR build + segmented reduce ----
    init_zero<<<(NNODES + 255) / 256, 256, 0, stream>>>(count, NNODES);
    edge_rank<<<NEDGES / 256, 256, 0, stream>>>(ei, count, rank, flags);
    scan_block_sums<<<SCAN_NB, 256, 0, stream>>>(count, bsum);
    scan_bsum<<<1, 512, 0, stream>>>(bsum, bscan, SCAN_NB);
    scan_final<<<SCAN_NB, 256, 0, stream>>>(count, bscan, offs);
    edge_scatter<<<NEDGES / 256, 256, 0, stream>>>(ei, rank, offs, sorted, flags);
    gather_finalize<<<(NNODES + 3) / 4, 256, 0, stream>>>(sorted, offs, count,
                                                          asrc, adst, hh, bias,
                                                          d_out, flags);
}

// Round 3
// 1061.341 us; speedup vs baseline: 3.2435x; 1.2071x over previous
//
#include <hip/hip_runtime.h>

// GAT pipeline, MI355X (gfx950) — round 6: zero-global-atomic edge phase.
// Round-5 counters: edge_rank 305us pinned at the measured ~20G/s device-scope
// atomic wall (6.4M atomics = 205MB of 32B fabric granules in WRITE_SIZE).
// Replaced rank+scan+scatter with a two-level counting sort using LDS atomics
// only: coarse 391-bucket partition (dst>>8) -> per-bucket fine CSR. Also
// deletes the 3 global scan kernels and init_zero (bucket_csr writes
// count/offs directly).

#define NNODES 100000
#define NEDGES 6400000
#define DIN    768
#define DH1    512
#define DH2    256
#define NEG_SLOPE 0.2f
#define LDSP   40     // padded LDS pitch (ushorts) in gemm
#define CHUNK  8192
#define NPART  782    // ceil(NEDGES/CHUNK)
#define NBUK   391    // ceil(NNODES/256)

typedef __bf16 bf16x8 __attribute__((ext_vector_type(8)));
typedef float  f32x4  __attribute__((ext_vector_type(4)));

__device__ __forceinline__ float bf2f(unsigned short h) {
    return __uint_as_float(((unsigned)h) << 16);
}
__device__ __forceinline__ unsigned short f2bf(float f) {
    unsigned u = __float_as_uint(f);
    unsigned r = u + 0x7FFFu + ((u >> 16) & 1u);   // round-nearest-even
    return (unsigned short)(r >> 16);
}
__device__ __forceinline__ float ldf(const void* p, int i, int isf32) {
    return isf32 ? ((const float*)p)[i] : bf2f(((const unsigned short*)p)[i]);
}
__device__ __forceinline__ uint4 packbf8(const float* p) {
    float4 u = *(const float4*)p;
    float4 v = *(const float4*)(p + 4);
    uint4 r;
    r.x = (unsigned)f2bf(u.x) | ((unsigned)f2bf(u.y) << 16);
    r.y = (unsigned)f2bf(u.z) | ((unsigned)f2bf(u.w) << 16);
    r.z = (unsigned)f2bf(v.x) | ((unsigned)f2bf(v.y) << 16);
    r.w = (unsigned)f2bf(v.z) | ((unsigned)f2bf(v.w) << 16);
    return r;
}

// flags: [0]=x_f32 [1]=We1_f32 [2]=We2_f32 [3]=Wlin_f32 [4]=Watt_f32
//        [5]=edge_i64 [15]=0 constant
__global__ void detect_dtypes(const unsigned short* x, const unsigned short* we1,
                              const unsigned short* we2, const unsigned short* wlin,
                              const unsigned short* watt, const int* ei, int* flags) {
    __shared__ int cnt;
    int b = blockIdx.x, t = threadIdx.x;
    if (t == 0) cnt = 0;
    __syncthreads();
    if (b < 5) {
        const unsigned short* p = (b == 0) ? x : (b == 1) ? we1 : (b == 2) ? we2
                                  : (b == 3) ? wlin : watt;
        int K = (b == 4) ? 96 : 512;
        int c = 0;
        for (int i = t; i < K; i += 256) {
            int e = (p[2 * i] >> 7) & 0xFF;
            if (e >= 0x66 && e <= 0x8C) c++;
        }
        atomicAdd(&cnt, c);
        __syncthreads();
        if (t == 0) flags[b] = (cnt * 10 < K * 6) ? 1 : 0;
    } else {
        int c = 0;
        for (int i = t; i < 2048; i += 256)
            if (ei[2 * i + 1] != 0) c++;
        atomicAdd(&cnt, c);
        __syncthreads();
        if (t == 0) { flags[5] = (cnt == 0) ? 1 : 0; flags[15] = 0; }
    }
}

__global__ void transpose_conv(const void* in, unsigned short* out, int K, int N,
                               const int* flags, int fidx) {
    int f32 = flags[fidx];
    int idx = blockIdx.x * 256 + threadIdx.x;
    if (idx >= K * N) return;
    int k = idx / N, n = idx - k * N;
    unsigned short v = f32 ? f2bf(((const float*)in)[idx])
                           : ((const unsigned short*)in)[idx];
    out[(size_t)n * K + k] = v;
}

template <bool RELU>
__global__ __launch_bounds__(256)
void gemm_bt(const void* __restrict__ A,
             const unsigned short* __restrict__ Bt,
             const unsigned short* __restrict__ bias,
             unsigned short* __restrict__ C,
             int M, int K, int N, const int* flags, int aidx, int nt_n) {
    __shared__ unsigned short sA[128 * LDSP];
    __shared__ unsigned short sB[128 * LDSP];
    const int af32 = flags[aidx];
    const int tid = threadIdx.x;

    // Bijective XCD-chunk swizzle; logical order N-fastest so blocks sharing
    // one A-panel co-run on one XCD and share it through that XCD's L2.
    const int nwg = gridDim.x;
    const int bid = blockIdx.x;
    const int xcd = bid & 7, bidx = bid >> 3;
    const int q = nwg >> 3, r = nwg & 7;
    const int logical = (xcd < r ? xcd * (q + 1) : r * (q + 1) + (xcd - r) * q) + bidx;
    const int m0 = (logical / nt_n) * 128;
    const int n0 = (logical % nt_n) * 128;

    const int srow = tid >> 2;
    const int scol = (tid & 3) * 8;
    int ar0 = m0 + srow;      if (ar0 >= M) ar0 = M - 1;
    int ar1 = m0 + 64 + srow; if (ar1 >= M) ar1 = M - 1;
    const unsigned short* Ah = (const unsigned short*)A;
    const float*          Af = (const float*)A;
    const unsigned short* gA0h = Ah + (size_t)ar0 * K + scol;
    const unsigned short* gA1h = Ah + (size_t)ar1 * K + scol;
    const float*          gA0f = Af + (size_t)ar0 * K + scol;
    const float*          gA1f = Af + (size_t)ar1 * K + scol;
    const unsigned short* gB0 = Bt + (size_t)(n0 + srow) * K + scol;
    const unsigned short* gB1 = Bt + (size_t)(n0 + 64 + srow) * K + scol;

    const int wave = tid >> 6, lane = tid & 63;
    const int wr = wave >> 1, wc = wave & 1;
    const int lr = lane & 15;
    const int lk = (lane >> 4) * 8;
    f32x4 acc[4][4] = {};

    for (int k0 = 0; k0 < K; k0 += 32) {
        uint4 a0, a1;
        if (af32) { a0 = packbf8(gA0f + k0); a1 = packbf8(gA1f + k0); }
        else      { a0 = *(const uint4*)(gA0h + k0); a1 = *(const uint4*)(gA1h + k0); }
        uint4 b0 = *(const uint4*)(gB0 + k0);
        uint4 b1 = *(const uint4*)(gB1 + k0);
        __syncthreads();
        *(uint4*)&sA[srow * LDSP + scol]        = a0;
        *(uint4*)&sA[(64 + srow) * LDSP + scol] = a1;
        *(uint4*)&sB[srow * LDSP + scol]        = b0;
        *(uint4*)&sB[(64 + srow) * LDSP + scol] = b1;
        __syncthreads();
        bf16x8 aF[4], bF[4];
#pragma unroll
        for (int i = 0; i < 4; i++) aF[i] = *(const bf16x8*)&sA[(wr * 64 + i * 16 + lr) * LDSP + lk];
#pragma unroll
        for (int j = 0; j < 4; j++) bF[j] = *(const bf16x8*)&sB[(wc * 64 + j * 16 + lr) * LDSP + lk];
#pragma unroll
        for (int i = 0; i < 4; i++)
#pragma unroll
            for (int j = 0; j < 4; j++)
                acc[i][j] = __builtin_amdgcn_mfma_f32_16x16x32_bf16(aF[i], bF[j], acc[i][j], 0, 0, 0);
    }

    float bv[4];
#pragma unroll
    for (int j = 0; j < 4; j++) bv[j] = bf2f(bias[n0 + wc * 64 + j * 16 + lr]);
#pragma unroll
    for (int i = 0; i < 4; i++) {
        int rbase = m0 + wr * 64 + i * 16 + (lane >> 4) * 4;
#pragma unroll
        for (int r = 0; r < 4; r++) {
            int row = rbase + r;
            if (row < M) {
                size_t base = (size_t)row * N + n0 + wc * 64 + lr;
#pragma unroll
                for (int j = 0; j < 4; j++) {
                    float v = acc[i][j][r] + bv[j];
                    if (RELU) v = fmaxf(v, 0.f);
                    C[base + j * 16] = f2bf(v);
                }
            }
        }
    }
}

__global__ __launch_bounds__(256)
void node_att(const unsigned short* __restrict__ h2,
              const void* __restrict__ Wlin,
              const unsigned short* __restrict__ blin,
              const void* __restrict__ Watt,
              const void* __restrict__ attS,
              const void* __restrict__ attD,
              float* __restrict__ hh, float* __restrict__ asrc,
              float* __restrict__ adst, const int* flags) {
    __shared__ float sW[256 * 32];
    __shared__ float sh2[8 * 256];
    __shared__ float sH[8 * 32];
    __shared__ float sHH[8 * 6];
    const int wlf = flags[3], waf = flags[4];
    const int tid = threadIdx.x;
    for (int i = tid; i < 256 * 32; i += 256) sW[i] = ldf(Wlin, i, wlf);
    const int n0 = blockIdx.x * 8;
    {
        int e = tid * 8;
        int r = e >> 8;
        int c = e & 255;
        uint4 v = *(const uint4*)(h2 + (size_t)(n0 + r) * 256 + c);
        float* o = &sh2[r * 256 + c];
        o[0] = __uint_as_float(v.x << 16); o[1] = __uint_as_float(v.x & 0xFFFF0000u);
        o[2] = __uint_as_float(v.y << 16); o[3] = __uint_as_float(v.y & 0xFFFF0000u);
        o[4] = __uint_as_float(v.z << 16); o[5] = __uint_as_float(v.z & 0xFFFF0000u);
        o[6] = __uint_as_float(v.w << 16); o[7] = __uint_as_float(v.w & 0xFFFF0000u);
    }
    __syncthreads();
    const int nl = tid >> 5;
    const int c  = tid & 31;
    float acc = bf2f(blin[c]);
    const float* hrow = &sh2[nl * 256];
#pragma unroll 8
    for (int k = 0; k < 256; k++) acc += hrow[k] * sW[k * 32 + c];
    sH[nl * 32 + c] = acc;
    __syncthreads();
    if (tid < 48) {
        int n = tid / 6, j = tid - (tid / 6) * 6;
        float s = 0.f;
#pragma unroll
        for (int k = 0; k < 32; k++) s += sH[n * 32 + k] * ldf(Watt, k * 6 + j, waf);
        sHH[n * 6 + j] = s;
        hh[(size_t)(n0 + n) * 6 + j] = s;
    }
    __syncthreads();
    if (tid < 16) {
        int n = tid >> 1, hd = tid & 1;
        float s = 0.f, d = 0.f;
#pragma unroll
        for (int cc = 0; cc < 3; cc++) {
            float v = sHH[n * 6 + hd * 3 + cc];
            s += v * ldf(attS, hd * 3 + cc, waf);
            d += v * ldf(attD, hd * 3 + cc, waf);
        }
        asrc[(size_t)(n0 + n) * 2 + hd] = s;
        adst[(size_t)(n0 + n) * 2 + hd] = d;
    }
}

// ---- edge phase: two-level counting sort, LDS atomics only ----

// P1: per-(bucket, block-chunk) coarse histogram of dst>>8.
__global__ __launch_bounds__(256)
void part_hist(const int* __restrict__ ei, unsigned* __restrict__ histG,
               const int* __restrict__ flags) {
    __shared__ unsigned h[NBUK];
    int k = blockIdx.x, t = threadIdx.x;
    for (int i = t; i < NBUK; i += 256) h[i] = 0;
    __syncthreads();
    int e0 = k * CHUNK;
    int e1 = e0 + CHUNK; if (e1 > NEDGES) e1 = NEDGES;
    int i64 = flags[5];
    for (int e = e0 + t; e < e1; e += 256) {
        int d = i64 ? (int)((const long long*)ei)[NEDGES + e] : ei[NEDGES + e];
        atomicAdd(&h[d >> 8], 1u);
    }
    __syncthreads();
    for (int i = t; i < NBUK; i += 256) histG[(size_t)i * NPART + k] = h[i];
}

// P2: per-bucket exclusive scan over block-chunks; emits bucket totals.
__global__ __launch_bounds__(256)
void part_scan(const unsigned* __restrict__ histG, unsigned* __restrict__ start,
               unsigned* __restrict__ btot) {
    int b = blockIdx.x, t = threadIdx.x;
    const unsigned* col = histG + (size_t)b * NPART;
    unsigned* out = start + (size_t)b * NPART;
    unsigned v[4]; unsigned sum = 0;
#pragma unroll
    for (int i = 0; i < 4; i++) {
        int k = t * 4 + i;
        unsigned x = (k < NPART) ? col[k] : 0;
        v[i] = x; sum += x;
    }
    __shared__ unsigned s[256];
    s[t] = sum; __syncthreads();
    for (int off = 1; off < 256; off <<= 1) {
        unsigned x = (t >= off) ? s[t - off] : 0;
        __syncthreads();
        s[t] += x;
        __syncthreads();
    }
    unsigned ex = s[t] - sum;
    unsigned run = ex;
#pragma unroll
    for (int i = 0; i < 4; i++) {
        int k = t * 4 + i;
        if (k < NPART) out[k] = run;
        run += v[i];
    }
    if (t == 255) btot[b] = s[255];
}

// P3: exclusive scan of bucket totals -> bucket bases (+ total at [NBUK]).
__global__ void bucket_base(const unsigned* __restrict__ btot, unsigned* __restrict__ bbase) {
    __shared__ unsigned s[512];
    int t = threadIdx.x;
    unsigned v = (t < NBUK) ? btot[t] : 0;
    s[t] = v;
    __syncthreads();
    for (int off = 1; off < 512; off <<= 1) {
        unsigned x = (t >= off) ? s[t - off] : 0;
        __syncthreads();
        s[t] += x;
        __syncthreads();
    }
    if (t < NBUK) bbase[t] = s[t] - v;
    if (t == NBUK - 1) bbase[NBUK] = s[t];
}

// P4: partition (src,dst) pairs by coarse bucket via LDS cursors.
__global__ __launch_bounds__(256)
void part_scatter(const int* __restrict__ ei, const unsigned* __restrict__ start,
                  const unsigned* __restrict__ bbase, uint2* __restrict__ pairs,
                  const int* __restrict__ flags) {
    __shared__ unsigned cur[NBUK];
    int k = blockIdx.x, t = threadIdx.x;
    for (int i = t; i < NBUK; i += 256)
        cur[i] = bbase[i] + start[(size_t)i * NPART + k];
    __syncthreads();
    int e0 = k * CHUNK;
    int e1 = e0 + CHUNK; if (e1 > NEDGES) e1 = NEDGES;
    int i64 = flags[5];
    for (int e = e0 + t; e < e1; e += 256) {
        int s, d;
        if (i64) {
            const long long* E = (const long long*)ei;
            s = (int)E[e];
            d = (int)E[NEDGES + e];
        } else {
            s = ei[e];
            d = ei[NEDGES + e];
        }
        unsigned pos = atomicAdd(&cur[d >> 8], 1u);
        pairs[pos] = make_uint2((unsigned)s, (unsigned)d);
    }
}

// P5: per-bucket fine CSR: counts + offsets (written straight to global) and
// src scatter into dst-sorted order. One block per 256-dst bucket.
__global__ __launch_bounds__(256)
void bucket_csr(const uint2* __restrict__ pairs, const unsigned* __restrict__ bbase,
                int* __restrict__ count, int* __restrict__ offs,
                int* __restrict__ sorted) {
    int b = blockIdx.x, t = threadIdx.x;
    unsigned e0 = bbase[b], e1 = bbase[b + 1];
    int d0n = b << 8;
    int nd = NNODES - d0n; if (nd > 256) nd = 256;
    __shared__ unsigned cnt[256], s[256], cur[256];
    cnt[t] = 0;
    __syncthreads();
    for (unsigned e = e0 + t; e < e1; e += 256)
        atomicAdd(&cnt[pairs[e].y & 255], 1u);
    __syncthreads();
    unsigned myc = cnt[t];
    s[t] = myc; __syncthreads();
    for (int off = 1; off < 256; off <<= 1) {
        unsigned x = (t >= off) ? s[t - off] : 0;
        __syncthreads();
        s[t] += x;
        __syncthreads();
    }
    unsigned ex = s[t] - myc;
    if (t < nd) {
        count[d0n + t] = (int)myc;
        offs[d0n + t]  = (int)(e0 + ex);
    }
    cur[t] = e0 + ex;
    __syncthreads();
    for (unsigned e = e0 + t; e < e1; e += 256) {
        uint2 p = pairs[e];
        unsigned pos = atomicAdd(&cur[p.y & 255], 1u);
        sorted[pos] = (int)p.x;
    }
}

// One wave per destination node: register accumulation + butterfly reduce,
// self-loop added analytically, softmax-normalize, head-mean, bias, store.
__global__ __launch_bounds__(256)
void gather_finalize(const int* __restrict__ sorted, const int* __restrict__ offs,
                     const int* __restrict__ count,
                     const float* __restrict__ asrc, const float* __restrict__ adst,
                     const float* __restrict__ hh,
                     const unsigned short* __restrict__ bias,
                     void* __restrict__ out, const int* __restrict__ flags) {
    int w = blockIdx.x * 4 + (threadIdx.x >> 6);
    if (w >= NNODES) return;
    int lane = threadIdx.x & 63;
    int base = offs[w];
    int cnt  = count[w];
    float2 ad = *(const float2*)(adst + 2 * (size_t)w);

    float d0 = 0.f, d1 = 0.f;
    float n0 = 0.f, n1 = 0.f, n2 = 0.f, n3 = 0.f, n4 = 0.f, n5 = 0.f;
    for (int k = lane; k < cnt; k += 64) {
        int s = sorted[base + k];
        float2 as = *(const float2*)(asrc + 2 * (size_t)s);
        float a0 = as.x + ad.x; a0 = a0 > 0.f ? a0 : NEG_SLOPE * a0;
        float a1 = as.y + ad.y; a1 = a1 > 0.f ? a1 : NEG_SLOPE * a1;
        float p0 = __expf(fminf(a0, 60.f));
        float p1 = __expf(fminf(a1, 60.f));
        const float* hs = hh + 6 * (size_t)s;
        d0 += p0; d1 += p1;
        n0 += p0 * hs[0]; n1 += p0 * hs[1]; n2 += p0 * hs[2];
        n3 += p1 * hs[3]; n4 += p1 * hs[4]; n5 += p1 * hs[5];
    }
#pragma unroll
    for (int m = 32; m > 0; m >>= 1) {
        d0 += __shfl_xor(d0, m, 64); d1 += __shfl_xor(d1, m, 64);
        n0 += __shfl_xor(n0, m, 64); n1 += __shfl_xor(n1, m, 64);
        n2 += __shfl_xor(n2, m, 64); n3 += __shfl_xor(n3, m, 64);
        n4 += __shfl_xor(n4, m, 64); n5 += __shfl_xor(n5, m, 64);
    }
    if (lane == 0) {
        // self-loop (s == w)
        float2 as = *(const float2*)(asrc + 2 * (size_t)w);
        float a0 = as.x + ad.x; a0 = a0 > 0.f ? a0 : NEG_SLOPE * a0;
        float a1 = as.y + ad.y; a1 = a1 > 0.f ? a1 : NEG_SLOPE * a1;
        float p0 = __expf(fminf(a0, 60.f));
        float p1 = __expf(fminf(a1, 60.f));
        const float* hw = hh + 6 * (size_t)w;
        d0 += p0; d1 += p1;
        n0 += p0 * hw[0]; n1 += p0 * hw[1]; n2 += p0 * hw[2];
        n3 += p1 * hw[3]; n4 += p1 * hw[4]; n5 += p1 * hw[5];

        float o0 = 0.5f * (n0 / d0 + n3 / d1) + bf2f(bias[0]);
        float o1 = 0.5f * (n1 / d0 + n4 / d1) + bf2f(bias[1]);
        float o2 = 0.5f * (n2 / d0 + n5 / d1) + bf2f(bias[2]);
        if (flags[0]) {
            float* o = (float*)out;
            o[3 * (size_t)w + 0] = o0; o[3 * (size_t)w + 1] = o1; o[3 * (size_t)w + 2] = o2;
        } else {
            unsigned short* o = (unsigned short*)out;
            o[3 * (size_t)w + 0] = f2bf(o0); o[3 * (size_t)w + 1] = f2bf(o1); o[3 * (size_t)w + 2] = f2bf(o2);
        }
    }
}

extern "C" void kernel_launch(void* const* d_in, const int* in_sizes, int n_in,
                              void* d_out, int out_size, void* d_ws, size_t ws_size,
                              hipStream_t stream) {
    const unsigned short* x    = (const unsigned short*)d_in[0];
    const int*            ei   = (const int*)d_in[1];
    const unsigned short* We1  = (const unsigned short*)d_in[2];
    const unsigned short* be1  = (const unsigned short*)d_in[3];
    const unsigned short* We2  = (const unsigned short*)d_in[4];
    const unsigned short* be2  = (const unsigned short*)d_in[5];
    const unsigned short* Wlin = (const unsigned short*)d_in[6];
    const unsigned short* blin = (const unsigned short*)d_in[7];
    const unsigned short* Watt = (const unsigned short*)d_in[8];
    const unsigned short* attS = (const unsigned short*)d_in[9];
    const unsigned short* attD = (const unsigned short*)d_in[10];
    const unsigned short* bias = (const unsigned short*)d_in[11];

    char* ws = (char*)d_ws;
    unsigned short* W1t   = (unsigned short*)(ws + 0);          //     786,432
    unsigned short* W2t   = (unsigned short*)(ws + 786432);     //     262,144
    unsigned short* h2    = (unsigned short*)(ws + 1048576);    //  51,200,000
    float*    hh    = (float*)(ws + 52248576);                  //   2,400,000
    float*    asrc  = (float*)(ws + 54648576);                  //     800,000
    float*    adst  = (float*)(ws + 55448576);                  //     800,000
    int*      count = (int*)(ws + 56248576);                    //     400,000
    int*      offs  = (int*)(ws + 56648576);                    //     400,000
    unsigned* btot  = (unsigned*)(ws + 57048576);               //       1,568
    unsigned* bbase = (unsigned*)(ws + 57052672);               //       1,568
    int*      flags = (int*)(ws + 59448576);                    //          64
    unsigned short* h1 = (unsigned short*)(ws + 59448640);      // 102,400,000 (dead after gemm2)
    // pairs/sorted/histG/start alias h1 (stream-serialized).
    uint2*    pairs  = (uint2*)(ws + 59448640);                 //  51,200,000
    int*      sorted = (int*)(ws + 110648640);                  //  25,600,000
    unsigned* histG  = (unsigned*)(ws + 136248640);             //   1,223,048
    unsigned* start  = (unsigned*)(ws + 137471744);             //   1,223,048 (end ~138.7MB)
    (void)ws_size; (void)in_sizes; (void)n_in; (void)out_size;

    detect_dtypes<<<6, 256, 0, stream>>>(x, We1, We2, Wlin, Watt, ei, flags);

    transpose_conv<<<(DIN * DH1 + 255) / 256, 256, 0, stream>>>(We1, W1t, DIN, DH1, flags, 1);
    transpose_conv<<<(DH1 * DH2 + 255) / 256, 256, 0, stream>>>(We2, W2t, DH1, DH2, flags, 2);

    dim3 blk(256);
    // 1-D grids; in-kernel XCD-chunk swizzle, logical order N-fastest.
    int nwg1 = ((NNODES + 127) / 128) * (DH1 / 128);   // 782*4 = 3128
    gemm_bt<true><<<nwg1, blk, 0, stream>>>(x, W1t, be1, h1, NNODES, DIN, DH1,
                                            flags, 0, DH1 / 128);
    int nwg2 = ((NNODES + 127) / 128) * (DH2 / 128);   // 782*2 = 1564
    gemm_bt<false><<<nwg2, blk, 0, stream>>>(h1, W2t, be2, h2, NNODES, DH1, DH2,
                                             flags, 15, DH2 / 128);

    node_att<<<NNODES / 8, 256, 0, stream>>>(h2, Wlin, blin, Watt, attS, attD,
                                             hh, asrc, adst, flags);

    // ---- edge phase: two-level counting sort (LDS atomics only) ----
    part_hist<<<NPART, 256, 0, stream>>>(ei, histG, flags);
    part_scan<<<NBUK, 256, 0, stream>>>(histG, start, btot);
    bucket_base<<<1, 512, 0, stream>>>(btot, bbase);
    part_scatter<<<NPART, 256, 0, stream>>>(ei, start, bbase, pairs, flags);
    bucket_csr<<<NBUK, 256, 0, stream>>>(pairs, bbase, count, offs, sorted);
    gather_finalize<<<(NNODES + 3) / 4, 256, 0, stream>>>(sorted, offs, count,
                                                          asrc, adst, hh, bias,
                                                          d_out, flags);
}